// Round 3
// baseline (3954.437 us; speedup 1.0000x reference)
//
#include <hip/hip_runtime.h>
#include <hip/hip_bf16.h>
#include <cstdint>

#define M_ROWS 16384

typedef __attribute__((ext_vector_type(8))) short short8;
typedef __attribute__((ext_vector_type(4))) float f32x4;

__device__ __forceinline__ unsigned long long umin64(unsigned long long a,
                                                     unsigned long long b) {
  return a < b ? a : b;
}

// ---------------------------------------------------------------------------
// fp32 GEMM (SA1/SA2 — feeds masks, must stay bit-identical to round 1/2).
// ---------------------------------------------------------------------------
__global__ __launch_bounds__(256) void gemm_bias_relu(
    const float* __restrict__ X, int ldx,
    const float* __restrict__ W,
    const float* __restrict__ bias,
    float* __restrict__ Y, int ldy,
    int N, int K)
{
  __shared__ __align__(16) float As[16][68];
  __shared__ __align__(16) float Bs[16][68];
  int tid = threadIdx.x;
  int tx = tid & 15, ty = tid >> 4;
  int m0 = blockIdx.y << 6, n0 = blockIdx.x << 6;
  float acc[4][4] = {};
  for (int k0 = 0; k0 < K; k0 += 16) {
#pragma unroll
    for (int i = 0; i < 4; i++) {
      int idx = tid + (i << 8);
      int m = idx >> 4, k = idx & 15;
      As[k][m] = (k0 + k < K) ? X[(size_t)(m0 + m) * ldx + k0 + k] : 0.f;
    }
#pragma unroll
    for (int i = 0; i < 4; i++) {
      int idx = tid + (i << 8);
      int n = idx & 63, k = idx >> 6;
      Bs[k][n] = (k0 + k < K) ? W[(size_t)(k0 + k) * N + n0 + n] : 0.f;
    }
    __syncthreads();
#pragma unroll
    for (int k = 0; k < 16; k++) {
      float4 a4 = *(const float4*)&As[k][ty << 2];
      float4 b4 = *(const float4*)&Bs[k][tx << 2];
      float av[4] = {a4.x, a4.y, a4.z, a4.w};
      float bv[4] = {b4.x, b4.y, b4.z, b4.w};
#pragma unroll
      for (int i = 0; i < 4; i++)
#pragma unroll
        for (int j = 0; j < 4; j++)
          acc[i][j] += av[i] * bv[j];
    }
    __syncthreads();
  }
  float4 bb = *(const float4*)&bias[n0 + (tx << 2)];
  float bv[4] = {bb.x, bb.y, bb.z, bb.w};
#pragma unroll
  for (int i = 0; i < 4; i++) {
    int m = m0 + (ty << 2) + i;
    float4 o;
    o.x = fmaxf(acc[i][0] + bv[0], 0.f);
    o.y = fmaxf(acc[i][1] + bv[1], 0.f);
    o.z = fmaxf(acc[i][2] + bv[2], 0.f);
    o.w = fmaxf(acc[i][3] + bv[3], 0.f);
    *(float4*)&Y[(size_t)m * ldy + n0 + (tx << 2)] = o;
  }
}

// ---------------------------------------------------------------------------
// Fused weight prep: 8 transposes (W KxN fp32 -> Wt NxK bf16) in one dispatch.
// ---------------------------------------------------------------------------
struct TJobs {
  const float* W[8];
  __hip_bfloat16* Wt[8];
  int K[8], N[8], bx[8], off[8];
};

__global__ __launch_bounds__(256) void transpose_cast_all(TJobs jb)
{
  __shared__ float tile[32][33];
  int bid = blockIdx.x;
  int j = 0;
#pragma unroll
  for (int t = 1; t < 8; t++)
    if (bid >= jb.off[t]) j = t;
  int rel = bid - jb.off[j];
  int K = jb.K[j], N = jb.N[j];
  const float* W = jb.W[j];
  __hip_bfloat16* Wt = jb.Wt[j];
  int n0 = (rel % jb.bx[j]) << 5, k0 = (rel / jb.bx[j]) << 5;
  int c = threadIdx.x & 31, i0 = threadIdx.x >> 5;
#pragma unroll
  for (int p = 0; p < 4; p++) {
    int i = i0 + p * 8;
    tile[i][c] = W[(size_t)(k0 + i) * N + n0 + c];
  }
  __syncthreads();
#pragma unroll
  for (int p = 0; p < 4; p++) {
    int r = i0 + p * 8;
    Wt[(size_t)(n0 + r) * K + k0 + c] = (__hip_bfloat16)tile[c][r];
  }
}

// ---------------------------------------------------------------------------
// bf16 MFMA GEMM (unchanged from round 2).
// ---------------------------------------------------------------------------
template <bool OUT_BF16>
__global__ __launch_bounds__(256) void gemm_mfma(
    const __hip_bfloat16* __restrict__ A, int lda,
    const __hip_bfloat16* __restrict__ Wt, int ldw,
    const float* __restrict__ bias,
    void* __restrict__ Y, int ldy, int N, int K)
{
  __shared__ __align__(16) short As[128][40];
  __shared__ __align__(16) short Bs[128][40];
  int tid = threadIdx.x;
  int wave = tid >> 6, lane = tid & 63;
  int quad = lane >> 4, l16 = lane & 15;
  int m0 = blockIdx.y << 7, n0 = blockIdx.x << 7;
  int wm = (wave >> 1) << 6, wn = (wave & 1) << 6;
  f32x4 acc[4][4] = {};
  const short* Ag = (const short*)A;
  const short* Bg = (const short*)Wt;
  int srow = tid >> 2, sq = tid & 3;
  for (int k0 = 0; k0 < K; k0 += 32) {
#pragma unroll
    for (int h = 0; h < 2; h++) {
      int r = srow + (h << 6);
      uint4 va = *(const uint4*)&Ag[(size_t)(m0 + r) * lda + k0 + sq * 8];
      *(uint4*)&As[r][sq * 8] = va;
      uint4 vb = *(const uint4*)&Bg[(size_t)(n0 + r) * ldw + k0 + sq * 8];
      *(uint4*)&Bs[r][sq * 8] = vb;
    }
    __syncthreads();
    short8 a[4], b[4];
#pragma unroll
    for (int mi = 0; mi < 4; mi++)
      a[mi] = *(const short8*)&As[wm + mi * 16 + l16][quad * 8];
#pragma unroll
    for (int ni = 0; ni < 4; ni++)
      b[ni] = *(const short8*)&Bs[wn + ni * 16 + l16][quad * 8];
#pragma unroll
    for (int mi = 0; mi < 4; mi++)
#pragma unroll
      for (int ni = 0; ni < 4; ni++)
        acc[mi][ni] = __builtin_amdgcn_mfma_f32_16x16x32_bf16(
            a[mi], b[ni], acc[mi][ni], 0, 0, 0);
    __syncthreads();
  }
  float bn[4];
#pragma unroll
  for (int ni = 0; ni < 4; ni++) bn[ni] = bias[n0 + wn + ni * 16 + l16];
#pragma unroll
  for (int mi = 0; mi < 4; mi++)
#pragma unroll
    for (int ni = 0; ni < 4; ni++) {
      int n = n0 + wn + ni * 16 + l16;
#pragma unroll
      for (int r = 0; r < 4; r++) {
        int m = m0 + wm + mi * 16 + quad * 4 + r;
        float v = fmaxf(acc[mi][ni][r] + bn[ni], 0.f);
        if (OUT_BF16)
          ((__hip_bfloat16*)Y)[(size_t)m * ldy + n] = (__hip_bfloat16)v;
        else
          ((float*)Y)[(size_t)m * ldy + n] = v;
      }
    }
}

// ---------------------------------------------------------------------------
// SA1 KNN v2: per-wave top-32 with shfl-only rounds (no syncthreads in the
// loop), then O(n^2) rank-merge of 4x32 candidates. Same 64-bit keys and
// ascending-rank accumulation as before -> bit-identical X1.
// ---------------------------------------------------------------------------
__global__ __launch_bounds__(256) void knn_mean_kernel(
    const float* __restrict__ X,
    const float* __restrict__ G1,
    float* __restrict__ X1,
    __hip_bfloat16* __restrict__ X1b)
{
  int q = blockIdx.x;
  int base = q & ~2047;
  int tid = threadIdx.x;
  int wave = tid >> 6, lane = tid & 63;
  __shared__ unsigned long long cand[128];
  __shared__ int selidx[32];
  float qx = X[(size_t)q * 2], qy = X[(size_t)q * 2 + 1];
  unsigned long long key[8];
  int jbase = wave << 9;
#pragma unroll
  for (int u = 0; u < 8; u++) {
    int j = jbase + (u << 6) + lane;
    float dx = X[(size_t)(base + j) * 2] - qx;
    float dy = X[(size_t)(base + j) * 2 + 1] - qy;
    float d2 = dx * dx + dy * dy;
    key[u] = ((unsigned long long)__float_as_uint(d2) << 32) | (unsigned)j;
  }
  unsigned long long lmin = key[0];
#pragma unroll
  for (int u = 1; u < 8; u++) lmin = umin64(lmin, key[u]);
  for (int r = 0; r < 32; r++) {
    unsigned long long m = lmin;
#pragma unroll
    for (int off = 32; off > 0; off >>= 1)
      m = umin64(m, __shfl_xor(m, off));
    if (lane == 0) cand[(wave << 5) + r] = m;
    if (lmin == m) {  // this lane held the winner (keys unique)
#pragma unroll
      for (int u = 0; u < 8; u++)
        if (key[u] == m) key[u] = ~0ULL;
      lmin = key[0];
#pragma unroll
      for (int u = 1; u < 8; u++) lmin = umin64(lmin, key[u]);
    }
  }
  __syncthreads();
  if (tid < 128) {
    unsigned long long c = cand[tid];
    int rank = 0;
    for (int i = 0; i < 128; i++) rank += (cand[i] < c);
    if (rank < 32) selidx[rank] = (int)(c & 0xffffffffULL);
  }
  __syncthreads();
  if (tid < 64) {
    float acc = 0.f;
#pragma unroll 4
    for (int s = 0; s < 32; s++)
      acc += G1[(size_t)(base + selidx[s]) * 64 + tid];
    float v = acc * (1.0f / 32.0f);
    X1[(size_t)q * 64 + tid] = v;
    X1b[(size_t)q * 64 + tid] = (__hip_bfloat16)v;
  }
}

// ---------------------------------------------------------------------------
// Ball-query pass 1 (identical math to round 2; +occupancy via launch bounds).
// ---------------------------------------------------------------------------
template <int C>
__global__ __launch_bounds__(256, 3) void ball_mask2(
    const float* __restrict__ F,
    unsigned long long* __restrict__ mask,
    float r2)
{
  __shared__ __align__(16) float As[16][132];
  __shared__ __align__(16) float Bs[16][132];
  int tid = threadIdx.x;
  int tx = tid & 15, ty = tid >> 4;
  int q0 = blockIdx.y << 7;
  int base = q0 & ~2047;
  int c0 = base + (blockIdx.x << 7);
  float acc[8][8] = {};
  for (int k0 = 0; k0 < C; k0 += 16) {
#pragma unroll
    for (int c = 0; c < 2; c++) {
      int idx = tid + (c << 8);
      int row = idx >> 2, qr = idx & 3;
      float4 va = *(const float4*)&F[(size_t)(q0 + row) * C + k0 + qr * 4];
      As[qr * 4 + 0][row] = va.x;
      As[qr * 4 + 1][row] = va.y;
      As[qr * 4 + 2][row] = va.z;
      As[qr * 4 + 3][row] = va.w;
      float4 vb = *(const float4*)&F[(size_t)(c0 + row) * C + k0 + qr * 4];
      Bs[qr * 4 + 0][row] = vb.x;
      Bs[qr * 4 + 1][row] = vb.y;
      Bs[qr * 4 + 2][row] = vb.z;
      Bs[qr * 4 + 3][row] = vb.w;
    }
    __syncthreads();
#pragma unroll
    for (int k = 0; k < 16; k++) {
      float av[8], bv[8];
      *(float4*)&av[0] = *(const float4*)&As[k][ty * 8];
      *(float4*)&av[4] = *(const float4*)&As[k][ty * 8 + 4];
      *(float4*)&bv[0] = *(const float4*)&Bs[k][tx * 4];
      *(float4*)&bv[4] = *(const float4*)&Bs[k][64 + tx * 4];
#pragma unroll
      for (int i = 0; i < 8; i++)
#pragma unroll
        for (int j = 0; j < 8; j++) {
          float d = av[i] - bv[j];
          acc[i][j] += d * d;
        }
    }
    __syncthreads();
  }
  int w0 = (blockIdx.x << 1);
#pragma unroll
  for (int i = 0; i < 8; i++) {
    unsigned long long wlo = 0, whi = 0;
#pragma unroll
    for (int j = 0; j < 4; j++) {
      if (acc[i][j] <= r2) wlo |= 1ULL << (tx * 4 + j);
      if (acc[i][4 + j] <= r2) whi |= 1ULL << (tx * 4 + j);
    }
#pragma unroll
    for (int s = 1; s <= 8; s <<= 1) {
      wlo |= __shfl_xor(wlo, s);
      whi |= __shfl_xor(whi, s);
    }
    if (tx == 0) {
      int q = q0 + ty * 8 + i;
      mask[(size_t)q * 32 + w0] = wlo;
      mask[(size_t)q * 32 + w0 + 1] = whi;
    }
  }
}

// ---------------------------------------------------------------------------
// Ball-query pass 2 v2: one wave decodes the mask to an index list (prefix
// popcount), then all threads run an unrollable weighted-sum loop. Same
// weights and ascending-index order -> bit-identical output.
// ---------------------------------------------------------------------------
__global__ void ball_gather_kernel(
    const unsigned long long* __restrict__ mask,
    const float* __restrict__ H, int CH,
    float* __restrict__ Yf, __hip_bfloat16* __restrict__ Yb,
    int ldy, int S)
{
  int q = blockIdx.x;
  int base = q & ~2047;
  int tid = threadIdx.x;
  __shared__ int idxl[64];
  __shared__ float wtab[64];
  __shared__ int scount;
  if (tid < 32) {
    unsigned long long w = mask[(size_t)q * 32 + tid];
    int cnt = __popcll(w);
    // inclusive scan over 32 lanes
    int inc = cnt;
#pragma unroll
    for (int off = 1; off < 32; off <<= 1) {
      int o = __shfl_up(inc, off);
      if (tid >= off) inc += o;
    }
    if (tid == 31) scount = inc;
    int p = inc - cnt;  // exclusive prefix = write position of my first member
    while (w && p < 64) {
      int j = (tid << 6) + __builtin_ctzll(w);
      w &= w - 1;
      idxl[p++] = j;
    }
  }
  __syncthreads();
  int c = scount;
  if (tid < 64) {
    int p = tid;
    int cnt = (p < c && p < S) ? ((S - 1 - p) / c + 1) : 0;
    wtab[p] = (float)cnt / (float)S;
  }
  __syncthreads();
  float acc = 0.f;
  int lim = c < S ? c : S;
#pragma unroll 4
  for (int s = 0; s < lim; s++)
    acc += wtab[s] * H[(size_t)(base + idxl[s]) * CH + tid];
  if (Yf) Yf[(size_t)q * ldy + tid] = acc;
  if (Yb) Yb[(size_t)q * ldy + tid] = (__hip_bfloat16)acc;
}

// ---------------------------------------------------------------------------
// Final head.
// ---------------------------------------------------------------------------
__global__ __launch_bounds__(128) void out_kernel(
    const float* __restrict__ F2,
    const float* __restrict__ w,
    const float* __restrict__ bias,
    float* __restrict__ out)
{
  int q = blockIdx.x, tid = threadIdx.x;
  float v = F2[(size_t)q * 128 + tid] * w[tid];
  for (int off = 32; off > 0; off >>= 1) v += __shfl_down(v, off);
  __shared__ float part[2];
  if ((tid & 63) == 0) part[tid >> 6] = v;
  __syncthreads();
  if (tid == 0) {
    float s = part[0] + part[1] + bias[0];
    out[q] = 1.f / (1.f + expf(-s));
  }
}

// ---------------------------------------------------------------------------
extern "C" void kernel_launch(void* const* d_in, const int* in_sizes, int n_in,
                              void* d_out, int out_size, void* d_ws,
                              size_t ws_size, hipStream_t stream)
{
  const float* x      = (const float*)d_in[0];
  const float* sa1_w0 = (const float*)d_in[1];
  const float* sa1_b0 = (const float*)d_in[2];
  const float* sa1_w1 = (const float*)d_in[3];
  const float* sa1_b1 = (const float*)d_in[4];
  const float* sa2_w0 = (const float*)d_in[5];
  const float* sa2_b0 = (const float*)d_in[6];
  const float* sa2_w1 = (const float*)d_in[7];
  const float* sa2_b1 = (const float*)d_in[8];
  const float* sa3_w0 = (const float*)d_in[9];
  const float* sa3_b0 = (const float*)d_in[10];
  const float* sa3_w1 = (const float*)d_in[11];
  const float* sa3_b1 = (const float*)d_in[12];
  const float* fp1_w0 = (const float*)d_in[13];
  const float* fp1_b0 = (const float*)d_in[14];
  const float* fp1_w1 = (const float*)d_in[15];
  const float* fp1_b1 = (const float*)d_in[16];
  const float* fp2_w0 = (const float*)d_in[17];
  const float* fp2_b0 = (const float*)d_in[18];
  const float* fp2_w1 = (const float*)d_in[19];
  const float* fp2_b1 = (const float*)d_in[20];
  const float* fc1_w  = (const float*)d_in[21];
  const float* fc1_b  = (const float*)d_in[22];
  const float* fc2_w  = (const float*)d_in[23];
  const float* fc2_b  = (const float*)d_in[24];
  const float* out_w  = (const float*)d_in[25];
  const float* out_b  = (const float*)d_in[26];
  float* out = (float*)d_out;

  const size_t M = M_ROWS;
  float* ws = (float*)d_ws;
  float* T   = ws;             // M*256
  float* G1  = ws + M * 256;   // M*64
  float* X1  = ws + M * 320;   // M*64
  float* X2  = ws + M * 384;   // M*128
  float* H2  = ws + M * 512;   // M*128
  float* H3  = ws + M * 640;   // M*256
  unsigned long long* MASK = (unsigned long long*)(ws + M * 896);  // M*32 u64
  __hip_bfloat16* X1b = (__hip_bfloat16*)(ws + M * 960);   // M*64
  __hip_bfloat16* X2b = (__hip_bfloat16*)(ws + M * 992);   // M*128
  __hip_bfloat16* TB  = (__hip_bfloat16*)(ws + M * 1056);  // M*512
  __hip_bfloat16* G   = (__hip_bfloat16*)(ws + M * 1312);  // M*1024
  __hip_bfloat16* H3b = (__hip_bfloat16*)(ws + M * 1824);  // M*256
  __hip_bfloat16* WB  = (__hip_bfloat16*)(ws + M * 1952);
  if (ws_size < (size_t)M * 1984 * sizeof(float)) return;
  __hip_bfloat16* w_sa3_0 = WB;               // 256x128
  __hip_bfloat16* w_sa3_1 = w_sa3_0 + 32768;  // 256x256
  __hip_bfloat16* w_fp1_0 = w_sa3_1 + 65536;  // 512x128
  __hip_bfloat16* w_fp1_1 = w_fp1_0 + 65536;  // 512x512
  __hip_bfloat16* w_fp2_0 = w_fp1_1 + 262144; // 256x64
  __hip_bfloat16* w_fp2_1 = w_fp2_0 + 16384;  // 256x256
  __hip_bfloat16* w_fc1   = w_fp2_1 + 65536;  // 256x1024
  __hip_bfloat16* w_fc2   = w_fc1 + 262144;   // 128x256

  dim3 blk(256);
  // Fused weight prep.
  TJobs jb;
  const float* srcs[8] = {sa3_w0, sa3_w1, fp1_w0, fp1_w1, fp2_w0, fp2_w1, fc1_w, fc2_w};
  __hip_bfloat16* dsts[8] = {w_sa3_0, w_sa3_1, w_fp1_0, w_fp1_1, w_fp2_0, w_fp2_1, w_fc1, w_fc2};
  int Ks[8] = {128, 256, 128, 512, 64, 256, 1024, 256};
  int Ns[8] = {256, 256, 512, 512, 256, 256, 256, 128};
  int off = 0;
  for (int i = 0; i < 8; i++) {
    jb.W[i] = srcs[i]; jb.Wt[i] = dsts[i];
    jb.K[i] = Ks[i]; jb.N[i] = Ns[i];
    jb.bx[i] = Ns[i] >> 5;
    jb.off[i] = off;
    off += (Ns[i] >> 5) * (Ks[i] >> 5);
  }
  transpose_cast_all<<<off, blk, 0, stream>>>(jb);

  // SA1 (fp32 exact).
  gemm_bias_relu<<<dim3(1, 256), blk, 0, stream>>>(x, 2, sa1_w0, sa1_b0, T, 64, 64, 2);
  gemm_bias_relu<<<dim3(1, 256), blk, 0, stream>>>(T, 64, sa1_w1, sa1_b1, G1, 64, 64, 64);
  knn_mean_kernel<<<16384, 256, 0, stream>>>(x, G1, X1, X1b);
  // SA2 (fp32 exact).
  gemm_bias_relu<<<dim3(2, 256), blk, 0, stream>>>(X1, 64, sa2_w0, sa2_b0, T, 128, 128, 64);
  gemm_bias_relu<<<dim3(2, 256), blk, 0, stream>>>(T, 128, sa2_w1, sa2_b1, H2, 128, 128, 128);
  ball_mask2<64><<<dim3(16, 128), blk, 0, stream>>>(X1, MASK, 0.2f * 0.2f);
  ball_gather_kernel<<<16384, 128, 0, stream>>>(MASK, H2, 128, X2, X2b, 128, 32);
  // SA3 MLP (bf16 MFMA).
  gemm_mfma<true><<<dim3(2, 128), blk, 0, stream>>>(X2b, 128, w_sa3_0, 128, sa3_b0, TB, 256, 256, 128);
  gemm_mfma<false><<<dim3(2, 128), blk, 0, stream>>>(TB, 256, w_sa3_1, 256, sa3_b1, H3, 256, 256, 256);
  ball_mask2<128><<<dim3(16, 128), blk, 0, stream>>>(X2, MASK, 0.4f * 0.4f);
  ball_gather_kernel<<<16384, 256, 0, stream>>>(MASK, H3, 256, nullptr, G + 768, 1024, 64);
  // FP1 (bf16).
  gemm_mfma<true><<<dim3(4, 128), blk, 0, stream>>>(X2b, 128, w_fp1_0, 128, fp1_b0, TB, 512, 512, 128);
  gemm_mfma<true><<<dim3(4, 128), blk, 0, stream>>>(TB, 512, w_fp1_1, 512, fp1_b1, G + 256, 1024, 512, 512);
  // FP2 (bf16).
  gemm_mfma<true><<<dim3(2, 128), blk, 0, stream>>>(X1b, 64, w_fp2_0, 64, fp2_b0, TB, 256, 256, 64);
  gemm_mfma<true><<<dim3(2, 128), blk, 0, stream>>>(TB, 256, w_fp2_1, 256, fp2_b1, G, 1024, 256, 256);
  // Head (bf16).
  gemm_mfma<true><<<dim3(2, 128), blk, 0, stream>>>(G, 1024, w_fc1, 1024, fc1_b, H3b, 256, 256, 1024);
  gemm_mfma<false><<<dim3(1, 128), blk, 0, stream>>>(H3b, 256, w_fc2, 256, fc2_b, H2, 128, 128, 256);
  out_kernel<<<16384, 128, 0, stream>>>(H2, out_w, out_b, out);
}

// Round 4
// 843.345 us; speedup vs baseline: 4.6890x; 4.6890x over previous
//
#include <hip/hip_runtime.h>
#include <hip/hip_bf16.h>
#include <cstdint>

#define M_ROWS 16384

typedef __attribute__((ext_vector_type(8))) short short8;
typedef __attribute__((ext_vector_type(4))) float f32x4;
typedef __attribute__((ext_vector_type(2))) float f32x2;

__device__ __forceinline__ unsigned long long umin64(unsigned long long a,
                                                     unsigned long long b) {
  return a < b ? a : b;
}

// ---------------------------------------------------------------------------
// fp32 GEMM (SA1/SA2 — feeds masks, bit-identical path).
// ---------------------------------------------------------------------------
__global__ __launch_bounds__(256) void gemm_bias_relu(
    const float* __restrict__ X, int ldx,
    const float* __restrict__ W,
    const float* __restrict__ bias,
    float* __restrict__ Y, int ldy,
    int N, int K)
{
  __shared__ __align__(16) float As[16][68];
  __shared__ __align__(16) float Bs[16][68];
  int tid = threadIdx.x;
  int tx = tid & 15, ty = tid >> 4;
  int m0 = blockIdx.y << 6, n0 = blockIdx.x << 6;
  float acc[4][4] = {};
  for (int k0 = 0; k0 < K; k0 += 16) {
#pragma unroll
    for (int i = 0; i < 4; i++) {
      int idx = tid + (i << 8);
      int m = idx >> 4, k = idx & 15;
      As[k][m] = (k0 + k < K) ? X[(size_t)(m0 + m) * ldx + k0 + k] : 0.f;
    }
#pragma unroll
    for (int i = 0; i < 4; i++) {
      int idx = tid + (i << 8);
      int n = idx & 63, k = idx >> 6;
      Bs[k][n] = (k0 + k < K) ? W[(size_t)(k0 + k) * N + n0 + n] : 0.f;
    }
    __syncthreads();
#pragma unroll
    for (int k = 0; k < 16; k++) {
      float4 a4 = *(const float4*)&As[k][ty << 2];
      float4 b4 = *(const float4*)&Bs[k][tx << 2];
      float av[4] = {a4.x, a4.y, a4.z, a4.w};
      float bv[4] = {b4.x, b4.y, b4.z, b4.w};
#pragma unroll
      for (int i = 0; i < 4; i++)
#pragma unroll
        for (int j = 0; j < 4; j++)
          acc[i][j] += av[i] * bv[j];
    }
    __syncthreads();
  }
  float4 bb = *(const float4*)&bias[n0 + (tx << 2)];
  float bv[4] = {bb.x, bb.y, bb.z, bb.w};
#pragma unroll
  for (int i = 0; i < 4; i++) {
    int m = m0 + (ty << 2) + i;
    float4 o;
    o.x = fmaxf(acc[i][0] + bv[0], 0.f);
    o.y = fmaxf(acc[i][1] + bv[1], 0.f);
    o.z = fmaxf(acc[i][2] + bv[2], 0.f);
    o.w = fmaxf(acc[i][3] + bv[3], 0.f);
    *(float4*)&Y[(size_t)m * ldy + n0 + (tx << 2)] = o;
  }
}

// ---------------------------------------------------------------------------
// Fused weight prep: 8 transposes (W KxN fp32 -> Wt NxK bf16) in one dispatch.
// ---------------------------------------------------------------------------
struct TJobs {
  const float* W[8];
  __hip_bfloat16* Wt[8];
  int K[8], N[8], bx[8], off[8];
};

__global__ __launch_bounds__(256) void transpose_cast_all(TJobs jb)
{
  __shared__ float tile[32][33];
  int bid = blockIdx.x;
  int j = 0;
#pragma unroll
  for (int t = 1; t < 8; t++)
    if (bid >= jb.off[t]) j = t;
  int rel = bid - jb.off[j];
  int K = jb.K[j], N = jb.N[j];
  const float* W = jb.W[j];
  __hip_bfloat16* Wt = jb.Wt[j];
  int n0 = (rel % jb.bx[j]) << 5, k0 = (rel / jb.bx[j]) << 5;
  int c = threadIdx.x & 31, i0 = threadIdx.x >> 5;
#pragma unroll
  for (int p = 0; p < 4; p++) {
    int i = i0 + p * 8;
    tile[i][c] = W[(size_t)(k0 + i) * N + n0 + c];
  }
  __syncthreads();
#pragma unroll
  for (int p = 0; p < 4; p++) {
    int r = i0 + p * 8;
    Wt[(size_t)(n0 + r) * K + k0 + c] = (__hip_bfloat16)tile[c][r];
  }
}

// ---------------------------------------------------------------------------
// bf16 MFMA GEMM (unchanged).
// ---------------------------------------------------------------------------
template <bool OUT_BF16>
__global__ __launch_bounds__(256) void gemm_mfma(
    const __hip_bfloat16* __restrict__ A, int lda,
    const __hip_bfloat16* __restrict__ Wt, int ldw,
    const float* __restrict__ bias,
    void* __restrict__ Y, int ldy, int N, int K)
{
  __shared__ __align__(16) short As[128][40];
  __shared__ __align__(16) short Bs[128][40];
  int tid = threadIdx.x;
  int wave = tid >> 6, lane = tid & 63;
  int quad = lane >> 4, l16 = lane & 15;
  int m0 = blockIdx.y << 7, n0 = blockIdx.x << 7;
  int wm = (wave >> 1) << 6, wn = (wave & 1) << 6;
  f32x4 acc[4][4] = {};
  const short* Ag = (const short*)A;
  const short* Bg = (const short*)Wt;
  int srow = tid >> 2, sq = tid & 3;
  for (int k0 = 0; k0 < K; k0 += 32) {
#pragma unroll
    for (int h = 0; h < 2; h++) {
      int r = srow + (h << 6);
      uint4 va = *(const uint4*)&Ag[(size_t)(m0 + r) * lda + k0 + sq * 8];
      *(uint4*)&As[r][sq * 8] = va;
      uint4 vb = *(const uint4*)&Bg[(size_t)(n0 + r) * ldw + k0 + sq * 8];
      *(uint4*)&Bs[r][sq * 8] = vb;
    }
    __syncthreads();
    short8 a[4], b[4];
#pragma unroll
    for (int mi = 0; mi < 4; mi++)
      a[mi] = *(const short8*)&As[wm + mi * 16 + l16][quad * 8];
#pragma unroll
    for (int ni = 0; ni < 4; ni++)
      b[ni] = *(const short8*)&Bs[wn + ni * 16 + l16][quad * 8];
#pragma unroll
    for (int mi = 0; mi < 4; mi++)
#pragma unroll
      for (int ni = 0; ni < 4; ni++)
        acc[mi][ni] = __builtin_amdgcn_mfma_f32_16x16x32_bf16(
            a[mi], b[ni], acc[mi][ni], 0, 0, 0);
    __syncthreads();
  }
  float bn[4];
#pragma unroll
  for (int ni = 0; ni < 4; ni++) bn[ni] = bias[n0 + wn + ni * 16 + l16];
#pragma unroll
  for (int mi = 0; mi < 4; mi++)
#pragma unroll
    for (int ni = 0; ni < 4; ni++) {
      int n = n0 + wn + ni * 16 + l16;
#pragma unroll
      for (int r = 0; r < 4; r++) {
        int m = m0 + wm + mi * 16 + quad * 4 + r;
        float v = fmaxf(acc[mi][ni][r] + bn[ni], 0.f);
        if (OUT_BF16)
          ((__hip_bfloat16*)Y)[(size_t)m * ldy + n] = (__hip_bfloat16)v;
        else
          ((float*)Y)[(size_t)m * ldy + n] = v;
      }
    }
}

// ---------------------------------------------------------------------------
// SA1 KNN v2 (round-3 version — shfl-only selection + rank merge).
// ---------------------------------------------------------------------------
__global__ __launch_bounds__(256) void knn_mean_kernel(
    const float* __restrict__ X,
    const float* __restrict__ G1,
    float* __restrict__ X1,
    __hip_bfloat16* __restrict__ X1b)
{
  int q = blockIdx.x;
  int base = q & ~2047;
  int tid = threadIdx.x;
  int wave = tid >> 6, lane = tid & 63;
  __shared__ unsigned long long cand[128];
  __shared__ int selidx[32];
  float qx = X[(size_t)q * 2], qy = X[(size_t)q * 2 + 1];
  unsigned long long key[8];
  int jbase = wave << 9;
#pragma unroll
  for (int u = 0; u < 8; u++) {
    int j = jbase + (u << 6) + lane;
    float dx = X[(size_t)(base + j) * 2] - qx;
    float dy = X[(size_t)(base + j) * 2 + 1] - qy;
    float d2 = dx * dx + dy * dy;
    key[u] = ((unsigned long long)__float_as_uint(d2) << 32) | (unsigned)j;
  }
  unsigned long long lmin = key[0];
#pragma unroll
  for (int u = 1; u < 8; u++) lmin = umin64(lmin, key[u]);
  for (int r = 0; r < 32; r++) {
    unsigned long long m = lmin;
#pragma unroll
    for (int off = 32; off > 0; off >>= 1)
      m = umin64(m, __shfl_xor(m, off));
    if (lane == 0) cand[(wave << 5) + r] = m;
    if (lmin == m) {
#pragma unroll
      for (int u = 0; u < 8; u++)
        if (key[u] == m) key[u] = ~0ULL;
      lmin = key[0];
#pragma unroll
      for (int u = 1; u < 8; u++) lmin = umin64(lmin, key[u]);
    }
  }
  __syncthreads();
  if (tid < 128) {
    unsigned long long c = cand[tid];
    int rank = 0;
    for (int i = 0; i < 128; i++) rank += (cand[i] < c);
    if (rank < 32) selidx[rank] = (int)(c & 0xffffffffULL);
  }
  __syncthreads();
  if (tid < 64) {
    float acc = 0.f;
#pragma unroll 4
    for (int s = 0; s < 32; s++)
      acc += G1[(size_t)(base + selidx[s]) * 64 + tid];
    float v = acc * (1.0f / 32.0f);
    X1[(size_t)q * 64 + tid] = v;
    X1b[(size_t)q * 64 + tid] = (__hip_bfloat16)v;
  }
}

// ---------------------------------------------------------------------------
// Ball-query pass 1 v3: round-2 structure (NO min-occupancy bound — 192 VGPR
// / 2 waves-per-SIMD is the working point; 256,3 spilled the acc tile and
// caused a 10x regression). Inner 8x8 recast as 8x(4 x float2) so LLVM
// selects packed fp32 (v_pk_add/v_pk_fma) — half the VALU issue slots,
// element-wise numerics identical (same fma contraction, ascending-k order).
// ---------------------------------------------------------------------------
template <int C>
__global__ __launch_bounds__(256) void ball_mask2(
    const float* __restrict__ F,
    unsigned long long* __restrict__ mask,
    float r2)
{
  __shared__ __align__(16) float As[16][132];
  __shared__ __align__(16) float Bs[16][132];
  int tid = threadIdx.x;
  int tx = tid & 15, ty = tid >> 4;
  int q0 = blockIdx.y << 7;
  int base = q0 & ~2047;
  int c0 = base + (blockIdx.x << 7);
  f32x2 acc2[8][4] = {};
  for (int k0 = 0; k0 < C; k0 += 16) {
#pragma unroll
    for (int c = 0; c < 2; c++) {
      int idx = tid + (c << 8);
      int row = idx >> 2, qr = idx & 3;
      float4 va = *(const float4*)&F[(size_t)(q0 + row) * C + k0 + qr * 4];
      As[qr * 4 + 0][row] = va.x;
      As[qr * 4 + 1][row] = va.y;
      As[qr * 4 + 2][row] = va.z;
      As[qr * 4 + 3][row] = va.w;
      float4 vb = *(const float4*)&F[(size_t)(c0 + row) * C + k0 + qr * 4];
      Bs[qr * 4 + 0][row] = vb.x;
      Bs[qr * 4 + 1][row] = vb.y;
      Bs[qr * 4 + 2][row] = vb.z;
      Bs[qr * 4 + 3][row] = vb.w;
    }
    __syncthreads();
#pragma unroll
    for (int k = 0; k < 16; k++) {
      float av[8];
      f32x2 bv2[4];
      *(float4*)&av[0] = *(const float4*)&As[k][ty * 8];
      *(float4*)&av[4] = *(const float4*)&As[k][ty * 8 + 4];
      *(float4*)&bv2[0] = *(const float4*)&Bs[k][tx * 4];
      *(float4*)&bv2[2] = *(const float4*)&Bs[k][64 + tx * 4];
#pragma unroll
      for (int i = 0; i < 8; i++) {
        f32x2 a2 = {av[i], av[i]};
#pragma unroll
        for (int j2 = 0; j2 < 4; j2++) {
          f32x2 d = a2 - bv2[j2];
          acc2[i][j2] += d * d;
        }
      }
    }
    __syncthreads();
  }
  int w0 = (blockIdx.x << 1);
#pragma unroll
  for (int i = 0; i < 8; i++) {
    unsigned long long wlo = 0, whi = 0;
#pragma unroll
    for (int j = 0; j < 4; j++) {
      float dlo = acc2[i][j >> 1][j & 1];
      float dhi = acc2[i][2 + (j >> 1)][j & 1];
      if (dlo <= r2) wlo |= 1ULL << (tx * 4 + j);
      if (dhi <= r2) whi |= 1ULL << (tx * 4 + j);
    }
#pragma unroll
    for (int s = 1; s <= 8; s <<= 1) {
      wlo |= __shfl_xor(wlo, s);
      whi |= __shfl_xor(whi, s);
    }
    if (tx == 0) {
      int q = q0 + ty * 8 + i;
      mask[(size_t)q * 32 + w0] = wlo;
      mask[(size_t)q * 32 + w0 + 1] = whi;
    }
  }
}

// ---------------------------------------------------------------------------
// Ball-query pass 2 v2 (round-3 version — wave decode + unrollable sum).
// ---------------------------------------------------------------------------
__global__ void ball_gather_kernel(
    const unsigned long long* __restrict__ mask,
    const float* __restrict__ H, int CH,
    float* __restrict__ Yf, __hip_bfloat16* __restrict__ Yb,
    int ldy, int S)
{
  int q = blockIdx.x;
  int base = q & ~2047;
  int tid = threadIdx.x;
  __shared__ int idxl[64];
  __shared__ float wtab[64];
  __shared__ int scount;
  if (tid < 32) {
    unsigned long long w = mask[(size_t)q * 32 + tid];
    int cnt = __popcll(w);
    int inc = cnt;
#pragma unroll
    for (int off = 1; off < 32; off <<= 1) {
      int o = __shfl_up(inc, off);
      if (tid >= off) inc += o;
    }
    if (tid == 31) scount = inc;
    int p = inc - cnt;
    while (w && p < 64) {
      int j = (tid << 6) + __builtin_ctzll(w);
      w &= w - 1;
      idxl[p++] = j;
    }
  }
  __syncthreads();
  int c = scount;
  if (tid < 64) {
    int p = tid;
    int cnt = (p < c && p < S) ? ((S - 1 - p) / c + 1) : 0;
    wtab[p] = (float)cnt / (float)S;
  }
  __syncthreads();
  float acc = 0.f;
  int lim = c < S ? c : S;
#pragma unroll 4
  for (int s = 0; s < lim; s++)
    acc += wtab[s] * H[(size_t)(base + idxl[s]) * CH + tid];
  if (Yf) Yf[(size_t)q * ldy + tid] = acc;
  if (Yb) Yb[(size_t)q * ldy + tid] = (__hip_bfloat16)acc;
}

// ---------------------------------------------------------------------------
// Final head.
// ---------------------------------------------------------------------------
__global__ __launch_bounds__(128) void out_kernel(
    const float* __restrict__ F2,
    const float* __restrict__ w,
    const float* __restrict__ bias,
    float* __restrict__ out)
{
  int q = blockIdx.x, tid = threadIdx.x;
  float v = F2[(size_t)q * 128 + tid] * w[tid];
  for (int off = 32; off > 0; off >>= 1) v += __shfl_down(v, off);
  __shared__ float part[2];
  if ((tid & 63) == 0) part[tid >> 6] = v;
  __syncthreads();
  if (tid == 0) {
    float s = part[0] + part[1] + bias[0];
    out[q] = 1.f / (1.f + expf(-s));
  }
}

// ---------------------------------------------------------------------------
extern "C" void kernel_launch(void* const* d_in, const int* in_sizes, int n_in,
                              void* d_out, int out_size, void* d_ws,
                              size_t ws_size, hipStream_t stream)
{
  const float* x      = (const float*)d_in[0];
  const float* sa1_w0 = (const float*)d_in[1];
  const float* sa1_b0 = (const float*)d_in[2];
  const float* sa1_w1 = (const float*)d_in[3];
  const float* sa1_b1 = (const float*)d_in[4];
  const float* sa2_w0 = (const float*)d_in[5];
  const float* sa2_b0 = (const float*)d_in[6];
  const float* sa2_w1 = (const float*)d_in[7];
  const float* sa2_b1 = (const float*)d_in[8];
  const float* sa3_w0 = (const float*)d_in[9];
  const float* sa3_b0 = (const float*)d_in[10];
  const float* sa3_w1 = (const float*)d_in[11];
  const float* sa3_b1 = (const float*)d_in[12];
  const float* fp1_w0 = (const float*)d_in[13];
  const float* fp1_b0 = (const float*)d_in[14];
  const float* fp1_w1 = (const float*)d_in[15];
  const float* fp1_b1 = (const float*)d_in[16];
  const float* fp2_w0 = (const float*)d_in[17];
  const float* fp2_b0 = (const float*)d_in[18];
  const float* fp2_w1 = (const float*)d_in[19];
  const float* fp2_b1 = (const float*)d_in[20];
  const float* fc1_w  = (const float*)d_in[21];
  const float* fc1_b  = (const float*)d_in[22];
  const float* fc2_w  = (const float*)d_in[23];
  const float* fc2_b  = (const float*)d_in[24];
  const float* out_w  = (const float*)d_in[25];
  const float* out_b  = (const float*)d_in[26];
  float* out = (float*)d_out;

  const size_t M = M_ROWS;
  float* ws = (float*)d_ws;
  float* T   = ws;             // M*256
  float* G1  = ws + M * 256;   // M*64
  float* X1  = ws + M * 320;   // M*64
  float* X2  = ws + M * 384;   // M*128
  float* H2  = ws + M * 512;   // M*128
  float* H3  = ws + M * 640;   // M*256
  unsigned long long* MASK = (unsigned long long*)(ws + M * 896);  // M*32 u64
  __hip_bfloat16* X1b = (__hip_bfloat16*)(ws + M * 960);   // M*64
  __hip_bfloat16* X2b = (__hip_bfloat16*)(ws + M * 992);   // M*128
  __hip_bfloat16* TB  = (__hip_bfloat16*)(ws + M * 1056);  // M*512
  __hip_bfloat16* G   = (__hip_bfloat16*)(ws + M * 1312);  // M*1024
  __hip_bfloat16* H3b = (__hip_bfloat16*)(ws + M * 1824);  // M*256
  __hip_bfloat16* WB  = (__hip_bfloat16*)(ws + M * 1952);
  if (ws_size < (size_t)M * 1984 * sizeof(float)) return;
  __hip_bfloat16* w_sa3_0 = WB;               // 256x128
  __hip_bfloat16* w_sa3_1 = w_sa3_0 + 32768;  // 256x256
  __hip_bfloat16* w_fp1_0 = w_sa3_1 + 65536;  // 512x128
  __hip_bfloat16* w_fp1_1 = w_fp1_0 + 65536;  // 512x512
  __hip_bfloat16* w_fp2_0 = w_fp1_1 + 262144; // 256x64
  __hip_bfloat16* w_fp2_1 = w_fp2_0 + 16384;  // 256x256
  __hip_bfloat16* w_fc1   = w_fp2_1 + 65536;  // 256x1024
  __hip_bfloat16* w_fc2   = w_fc1 + 262144;   // 128x256

  dim3 blk(256);
  TJobs jb;
  const float* srcs[8] = {sa3_w0, sa3_w1, fp1_w0, fp1_w1, fp2_w0, fp2_w1, fc1_w, fc2_w};
  __hip_bfloat16* dsts[8] = {w_sa3_0, w_sa3_1, w_fp1_0, w_fp1_1, w_fp2_0, w_fp2_1, w_fc1, w_fc2};
  int Ks[8] = {128, 256, 128, 512, 64, 256, 1024, 256};
  int Ns[8] = {256, 256, 512, 512, 256, 256, 256, 128};
  int off = 0;
  for (int i = 0; i < 8; i++) {
    jb.W[i] = srcs[i]; jb.Wt[i] = dsts[i];
    jb.K[i] = Ks[i]; jb.N[i] = Ns[i];
    jb.bx[i] = Ns[i] >> 5;
    jb.off[i] = off;
    off += (Ns[i] >> 5) * (Ks[i] >> 5);
  }
  transpose_cast_all<<<off, blk, 0, stream>>>(jb);

  // SA1 (fp32 exact).
  gemm_bias_relu<<<dim3(1, 256), blk, 0, stream>>>(x, 2, sa1_w0, sa1_b0, T, 64, 64, 2);
  gemm_bias_relu<<<dim3(1, 256), blk, 0, stream>>>(T, 64, sa1_w1, sa1_b1, G1, 64, 64, 64);
  knn_mean_kernel<<<16384, 256, 0, stream>>>(x, G1, X1, X1b);
  // SA2 (fp32 exact).
  gemm_bias_relu<<<dim3(2, 256), blk, 0, stream>>>(X1, 64, sa2_w0, sa2_b0, T, 128, 128, 64);
  gemm_bias_relu<<<dim3(2, 256), blk, 0, stream>>>(T, 128, sa2_w1, sa2_b1, H2, 128, 128, 128);
  ball_mask2<64><<<dim3(16, 128), blk, 0, stream>>>(X1, MASK, 0.2f * 0.2f);
  ball_gather_kernel<<<16384, 128, 0, stream>>>(MASK, H2, 128, X2, X2b, 128, 32);
  // SA3 MLP (bf16 MFMA).
  gemm_mfma<true><<<dim3(2, 128), blk, 0, stream>>>(X2b, 128, w_sa3_0, 128, sa3_b0, TB, 256, 256, 128);
  gemm_mfma<false><<<dim3(2, 128), blk, 0, stream>>>(TB, 256, w_sa3_1, 256, sa3_b1, H3, 256, 256, 256);
  ball_mask2<128><<<dim3(16, 128), blk, 0, stream>>>(X2, MASK, 0.4f * 0.4f);
  ball_gather_kernel<<<16384, 256, 0, stream>>>(MASK, H3, 256, nullptr, G + 768, 1024, 64);
  // FP1 (bf16).
  gemm_mfma<true><<<dim3(4, 128), blk, 0, stream>>>(X2b, 128, w_fp1_0, 128, fp1_b0, TB, 512, 512, 128);
  gemm_mfma<true><<<dim3(4, 128), blk, 0, stream>>>(TB, 512, w_fp1_1, 512, fp1_b1, G + 256, 1024, 512, 512);
  // FP2 (bf16).
  gemm_mfma<true><<<dim3(2, 128), blk, 0, stream>>>(X1b, 64, w_fp2_0, 64, fp2_b0, TB, 256, 256, 64);
  gemm_mfma<true><<<dim3(2, 128), blk, 0, stream>>>(TB, 256, w_fp2_1, 256, fp2_b1, G, 1024, 256, 256);
  // Head (bf16).
  gemm_mfma<true><<<dim3(2, 128), blk, 0, stream>>>(G, 1024, w_fc1, 1024, fc1_b, H3b, 256, 256, 1024);
  gemm_mfma<false><<<dim3(1, 128), blk, 0, stream>>>(H3b, 256, w_fc2, 256, fc2_b, H2, 128, 128, 256);
  out_kernel<<<16384, 128, 0, stream>>>(H2, out_w, out_b, out);
}

// Round 5
// 628.744 us; speedup vs baseline: 6.2894x; 1.3413x over previous
//
#include <hip/hip_runtime.h>
#include <hip/hip_bf16.h>
#include <cstdint>

#define M_ROWS 16384

typedef __attribute__((ext_vector_type(8))) short short8;
typedef __attribute__((ext_vector_type(4))) float f32x4;
typedef __attribute__((ext_vector_type(2))) float f32x2;

__device__ __forceinline__ unsigned long long umin64(unsigned long long a,
                                                     unsigned long long b) {
  return a < b ? a : b;
}

// ---------------------------------------------------------------------------
// fp32 GEMM (SA1/SA2 — feeds masks, bit-identical path).
// ---------------------------------------------------------------------------
__global__ __launch_bounds__(256) void gemm_bias_relu(
    const float* __restrict__ X, int ldx,
    const float* __restrict__ W,
    const float* __restrict__ bias,
    float* __restrict__ Y, int ldy,
    int N, int K)
{
  __shared__ __align__(16) float As[16][68];
  __shared__ __align__(16) float Bs[16][68];
  int tid = threadIdx.x;
  int tx = tid & 15, ty = tid >> 4;
  int m0 = blockIdx.y << 6, n0 = blockIdx.x << 6;
  float acc[4][4] = {};
  for (int k0 = 0; k0 < K; k0 += 16) {
#pragma unroll
    for (int i = 0; i < 4; i++) {
      int idx = tid + (i << 8);
      int m = idx >> 4, k = idx & 15;
      As[k][m] = (k0 + k < K) ? X[(size_t)(m0 + m) * ldx + k0 + k] : 0.f;
    }
#pragma unroll
    for (int i = 0; i < 4; i++) {
      int idx = tid + (i << 8);
      int n = idx & 63, k = idx >> 6;
      Bs[k][n] = (k0 + k < K) ? W[(size_t)(k0 + k) * N + n0 + n] : 0.f;
    }
    __syncthreads();
#pragma unroll
    for (int k = 0; k < 16; k++) {
      float4 a4 = *(const float4*)&As[k][ty << 2];
      float4 b4 = *(const float4*)&Bs[k][tx << 2];
      float av[4] = {a4.x, a4.y, a4.z, a4.w};
      float bv[4] = {b4.x, b4.y, b4.z, b4.w};
#pragma unroll
      for (int i = 0; i < 4; i++)
#pragma unroll
        for (int j = 0; j < 4; j++)
          acc[i][j] += av[i] * bv[j];
    }
    __syncthreads();
  }
  float4 bb = *(const float4*)&bias[n0 + (tx << 2)];
  float bv[4] = {bb.x, bb.y, bb.z, bb.w};
#pragma unroll
  for (int i = 0; i < 4; i++) {
    int m = m0 + (ty << 2) + i;
    float4 o;
    o.x = fmaxf(acc[i][0] + bv[0], 0.f);
    o.y = fmaxf(acc[i][1] + bv[1], 0.f);
    o.z = fmaxf(acc[i][2] + bv[2], 0.f);
    o.w = fmaxf(acc[i][3] + bv[3], 0.f);
    *(float4*)&Y[(size_t)m * ldy + n0 + (tx << 2)] = o;
  }
}

// ---------------------------------------------------------------------------
// Fused weight prep: 8 transposes (W KxN fp32 -> Wt NxK bf16) in one dispatch.
// ---------------------------------------------------------------------------
struct TJobs {
  const float* W[8];
  __hip_bfloat16* Wt[8];
  int K[8], N[8], bx[8], off[8];
};

__global__ __launch_bounds__(256) void transpose_cast_all(TJobs jb)
{
  __shared__ float tile[32][33];
  int bid = blockIdx.x;
  int j = 0;
#pragma unroll
  for (int t = 1; t < 8; t++)
    if (bid >= jb.off[t]) j = t;
  int rel = bid - jb.off[j];
  int K = jb.K[j], N = jb.N[j];
  const float* W = jb.W[j];
  __hip_bfloat16* Wt = jb.Wt[j];
  int n0 = (rel % jb.bx[j]) << 5, k0 = (rel / jb.bx[j]) << 5;
  int c = threadIdx.x & 31, i0 = threadIdx.x >> 5;
#pragma unroll
  for (int p = 0; p < 4; p++) {
    int i = i0 + p * 8;
    tile[i][c] = W[(size_t)(k0 + i) * N + n0 + c];
  }
  __syncthreads();
#pragma unroll
  for (int p = 0; p < 4; p++) {
    int r = i0 + p * 8;
    Wt[(size_t)(n0 + r) * K + k0 + c] = (__hip_bfloat16)tile[c][r];
  }
}

// ---------------------------------------------------------------------------
// bf16 MFMA GEMM (unchanged).
// ---------------------------------------------------------------------------
template <bool OUT_BF16>
__global__ __launch_bounds__(256) void gemm_mfma(
    const __hip_bfloat16* __restrict__ A, int lda,
    const __hip_bfloat16* __restrict__ Wt, int ldw,
    const float* __restrict__ bias,
    void* __restrict__ Y, int ldy, int N, int K)
{
  __shared__ __align__(16) short As[128][40];
  __shared__ __align__(16) short Bs[128][40];
  int tid = threadIdx.x;
  int wave = tid >> 6, lane = tid & 63;
  int quad = lane >> 4, l16 = lane & 15;
  int m0 = blockIdx.y << 7, n0 = blockIdx.x << 7;
  int wm = (wave >> 1) << 6, wn = (wave & 1) << 6;
  f32x4 acc[4][4] = {};
  const short* Ag = (const short*)A;
  const short* Bg = (const short*)Wt;
  int srow = tid >> 2, sq = tid & 3;
  for (int k0 = 0; k0 < K; k0 += 32) {
#pragma unroll
    for (int h = 0; h < 2; h++) {
      int r = srow + (h << 6);
      uint4 va = *(const uint4*)&Ag[(size_t)(m0 + r) * lda + k0 + sq * 8];
      *(uint4*)&As[r][sq * 8] = va;
      uint4 vb = *(const uint4*)&Bg[(size_t)(n0 + r) * ldw + k0 + sq * 8];
      *(uint4*)&Bs[r][sq * 8] = vb;
    }
    __syncthreads();
    short8 a[4], b[4];
#pragma unroll
    for (int mi = 0; mi < 4; mi++)
      a[mi] = *(const short8*)&As[wm + mi * 16 + l16][quad * 8];
#pragma unroll
    for (int ni = 0; ni < 4; ni++)
      b[ni] = *(const short8*)&Bs[wn + ni * 16 + l16][quad * 8];
#pragma unroll
    for (int mi = 0; mi < 4; mi++)
#pragma unroll
      for (int ni = 0; ni < 4; ni++)
        acc[mi][ni] = __builtin_amdgcn_mfma_f32_16x16x32_bf16(
            a[mi], b[ni], acc[mi][ni], 0, 0, 0);
    __syncthreads();
  }
  float bn[4];
#pragma unroll
  for (int ni = 0; ni < 4; ni++) bn[ni] = bias[n0 + wn + ni * 16 + l16];
#pragma unroll
  for (int mi = 0; mi < 4; mi++)
#pragma unroll
    for (int ni = 0; ni < 4; ni++) {
      int n = n0 + wn + ni * 16 + l16;
#pragma unroll
      for (int r = 0; r < 4; r++) {
        int m = m0 + wm + mi * 16 + quad * 4 + r;
        float v = fmaxf(acc[mi][ni][r] + bn[ni], 0.f);
        if (OUT_BF16)
          ((__hip_bfloat16*)Y)[(size_t)m * ldy + n] = (__hip_bfloat16)v;
        else
          ((float*)Y)[(size_t)m * ldy + n] = v;
      }
    }
}

// ---------------------------------------------------------------------------
// SA1 KNN v3: threshold selection. T = 32nd-smallest of the 256 per-thread
// min-keys (a valid cutoff: those 32 thread-mins are keys <= T). Survivors
// (expected ~34 of 2048; buffer sized 2048 = always safe) get exact ranks by
// O(s^2) unique-key comparison. Selected set and rank order bit-identical to
// the iterative version; the 32-round 64-bit shfl butterfly is gone.
// ---------------------------------------------------------------------------
__global__ __launch_bounds__(256) void knn_mean_kernel(
    const float* __restrict__ X,
    const float* __restrict__ G1,
    float* __restrict__ X1,
    __hip_bfloat16* __restrict__ X1b)
{
  int q = blockIdx.x;
  int base = q & ~2047;
  int tid = threadIdx.x;
  __shared__ unsigned long long lmins[256];
  __shared__ unsigned long long surv[2048];
  __shared__ unsigned long long thr;
  __shared__ int scnt;
  __shared__ int selidx[32];
  if (tid == 0) scnt = 0;
  float qx = X[(size_t)q * 2], qy = X[(size_t)q * 2 + 1];
  unsigned long long key[8];
#pragma unroll
  for (int u = 0; u < 8; u++) {
    int j = (u << 8) + tid;
    float dx = X[(size_t)(base + j) * 2] - qx;
    float dy = X[(size_t)(base + j) * 2 + 1] - qy;
    float d2 = dx * dx + dy * dy;
    key[u] = ((unsigned long long)__float_as_uint(d2) << 32) | (unsigned)j;
  }
  unsigned long long lm = key[0];
#pragma unroll
  for (int u = 1; u < 8; u++) lm = umin64(lm, key[u]);
  lmins[tid] = lm;
  __syncthreads();
  // Rank my thread-min among all 256 (LDS broadcast reads; unique keys ->
  // ranks are a permutation, exactly one rank==31).
  int rank = 0;
  for (int i = 0; i < 256; i++) rank += (lmins[i] < lm);
  if (rank == 31) thr = lm;
  __syncthreads();
  unsigned long long T = thr;
#pragma unroll
  for (int u = 0; u < 8; u++) {
    if (key[u] <= T) {
      int p = atomicAdd(&scnt, 1);
      surv[p] = key[u];
    }
  }
  __syncthreads();
  int s = scnt;  // >= 32 guaranteed
  for (int i = tid; i < s; i += 256) {
    unsigned long long c = surv[i];
    int r = 0;
    for (int j2 = 0; j2 < s; j2++) r += (surv[j2] < c);
    if (r < 32) selidx[r] = (int)(c & 0xffffffffULL);
  }
  __syncthreads();
  if (tid < 64) {
    float acc = 0.f;
#pragma unroll 4
    for (int sI = 0; sI < 32; sI++)
      acc += G1[(size_t)(base + selidx[sI]) * 64 + tid];
    float v = acc * (1.0f / 32.0f);
    X1[(size_t)q * 64 + tid] = v;
    X1b[(size_t)q * 64 + tid] = (__hip_bfloat16)v;
  }
}

// ---------------------------------------------------------------------------
// Ball-query pass 1 v3 (round-4 version: packed fp32, no min-occupancy bound
// — 256,3 spilled the acc tile and caused a 10x regression; don't re-add).
// ---------------------------------------------------------------------------
template <int C>
__global__ __launch_bounds__(256) void ball_mask2(
    const float* __restrict__ F,
    unsigned long long* __restrict__ mask,
    float r2)
{
  __shared__ __align__(16) float As[16][132];
  __shared__ __align__(16) float Bs[16][132];
  int tid = threadIdx.x;
  int tx = tid & 15, ty = tid >> 4;
  int q0 = blockIdx.y << 7;
  int base = q0 & ~2047;
  int c0 = base + (blockIdx.x << 7);
  f32x2 acc2[8][4] = {};
  for (int k0 = 0; k0 < C; k0 += 16) {
#pragma unroll
    for (int c = 0; c < 2; c++) {
      int idx = tid + (c << 8);
      int row = idx >> 2, qr = idx & 3;
      float4 va = *(const float4*)&F[(size_t)(q0 + row) * C + k0 + qr * 4];
      As[qr * 4 + 0][row] = va.x;
      As[qr * 4 + 1][row] = va.y;
      As[qr * 4 + 2][row] = va.z;
      As[qr * 4 + 3][row] = va.w;
      float4 vb = *(const float4*)&F[(size_t)(c0 + row) * C + k0 + qr * 4];
      Bs[qr * 4 + 0][row] = vb.x;
      Bs[qr * 4 + 1][row] = vb.y;
      Bs[qr * 4 + 2][row] = vb.z;
      Bs[qr * 4 + 3][row] = vb.w;
    }
    __syncthreads();
#pragma unroll
    for (int k = 0; k < 16; k++) {
      float av[8];
      f32x2 bv2[4];
      *(float4*)&av[0] = *(const float4*)&As[k][ty * 8];
      *(float4*)&av[4] = *(const float4*)&As[k][ty * 8 + 4];
      *(float4*)&bv2[0] = *(const float4*)&Bs[k][tx * 4];
      *(float4*)&bv2[2] = *(const float4*)&Bs[k][64 + tx * 4];
#pragma unroll
      for (int i = 0; i < 8; i++) {
        f32x2 a2 = {av[i], av[i]};
#pragma unroll
        for (int j2 = 0; j2 < 4; j2++) {
          f32x2 d = a2 - bv2[j2];
          acc2[i][j2] += d * d;
        }
      }
    }
    __syncthreads();
  }
  int w0 = (blockIdx.x << 1);
#pragma unroll
  for (int i = 0; i < 8; i++) {
    unsigned long long wlo = 0, whi = 0;
#pragma unroll
    for (int j = 0; j < 4; j++) {
      float dlo = acc2[i][j >> 1][j & 1];
      float dhi = acc2[i][2 + (j >> 1)][j & 1];
      if (dlo <= r2) wlo |= 1ULL << (tx * 4 + j);
      if (dhi <= r2) whi |= 1ULL << (tx * 4 + j);
    }
#pragma unroll
    for (int s = 1; s <= 8; s <<= 1) {
      wlo |= __shfl_xor(wlo, s);
      whi |= __shfl_xor(whi, s);
    }
    if (tx == 0) {
      int q = q0 + ty * 8 + i;
      mask[(size_t)q * 32 + w0] = wlo;
      mask[(size_t)q * 32 + w0 + 1] = whi;
    }
  }
}

// ---------------------------------------------------------------------------
// Ball-query pass 2 (round-3/4 version — wave decode + unrollable sum).
// ---------------------------------------------------------------------------
__global__ void ball_gather_kernel(
    const unsigned long long* __restrict__ mask,
    const float* __restrict__ H, int CH,
    float* __restrict__ Yf, __hip_bfloat16* __restrict__ Yb,
    int ldy, int S)
{
  int q = blockIdx.x;
  int base = q & ~2047;
  int tid = threadIdx.x;
  __shared__ int idxl[64];
  __shared__ float wtab[64];
  __shared__ int scount;
  if (tid < 32) {
    unsigned long long w = mask[(size_t)q * 32 + tid];
    int cnt = __popcll(w);
    int inc = cnt;
#pragma unroll
    for (int off = 1; off < 32; off <<= 1) {
      int o = __shfl_up(inc, off);
      if (tid >= off) inc += o;
    }
    if (tid == 31) scount = inc;
    int p = inc - cnt;
    while (w && p < 64) {
      int j = (tid << 6) + __builtin_ctzll(w);
      w &= w - 1;
      idxl[p++] = j;
    }
  }
  __syncthreads();
  int c = scount;
  if (tid < 64) {
    int p = tid;
    int cnt = (p < c && p < S) ? ((S - 1 - p) / c + 1) : 0;
    wtab[p] = (float)cnt / (float)S;
  }
  __syncthreads();
  float acc = 0.f;
  int lim = c < S ? c : S;
#pragma unroll 4
  for (int s = 0; s < lim; s++)
    acc += wtab[s] * H[(size_t)(base + idxl[s]) * CH + tid];
  if (Yf) Yf[(size_t)q * ldy + tid] = acc;
  if (Yb) Yb[(size_t)q * ldy + tid] = (__hip_bfloat16)acc;
}

// ---------------------------------------------------------------------------
// Final head.
// ---------------------------------------------------------------------------
__global__ __launch_bounds__(128) void out_kernel(
    const float* __restrict__ F2,
    const float* __restrict__ w,
    const float* __restrict__ bias,
    float* __restrict__ out)
{
  int q = blockIdx.x, tid = threadIdx.x;
  float v = F2[(size_t)q * 128 + tid] * w[tid];
  for (int off = 32; off > 0; off >>= 1) v += __shfl_down(v, off);
  __shared__ float part[2];
  if ((tid & 63) == 0) part[tid >> 6] = v;
  __syncthreads();
  if (tid == 0) {
    float s = part[0] + part[1] + bias[0];
    out[q] = 1.f / (1.f + expf(-s));
  }
}

// ---------------------------------------------------------------------------
extern "C" void kernel_launch(void* const* d_in, const int* in_sizes, int n_in,
                              void* d_out, int out_size, void* d_ws,
                              size_t ws_size, hipStream_t stream)
{
  const float* x      = (const float*)d_in[0];
  const float* sa1_w0 = (const float*)d_in[1];
  const float* sa1_b0 = (const float*)d_in[2];
  const float* sa1_w1 = (const float*)d_in[3];
  const float* sa1_b1 = (const float*)d_in[4];
  const float* sa2_w0 = (const float*)d_in[5];
  const float* sa2_b0 = (const float*)d_in[6];
  const float* sa2_w1 = (const float*)d_in[7];
  const float* sa2_b1 = (const float*)d_in[8];
  const float* sa3_w0 = (const float*)d_in[9];
  const float* sa3_b0 = (const float*)d_in[10];
  const float* sa3_w1 = (const float*)d_in[11];
  const float* sa3_b1 = (const float*)d_in[12];
  const float* fp1_w0 = (const float*)d_in[13];
  const float* fp1_b0 = (const float*)d_in[14];
  const float* fp1_w1 = (const float*)d_in[15];
  const float* fp1_b1 = (const float*)d_in[16];
  const float* fp2_w0 = (const float*)d_in[17];
  const float* fp2_b0 = (const float*)d_in[18];
  const float* fp2_w1 = (const float*)d_in[19];
  const float* fp2_b1 = (const float*)d_in[20];
  const float* fc1_w  = (const float*)d_in[21];
  const float* fc1_b  = (const float*)d_in[22];
  const float* fc2_w  = (const float*)d_in[23];
  const float* fc2_b  = (const float*)d_in[24];
  const float* out_w  = (const float*)d_in[25];
  const float* out_b  = (const float*)d_in[26];
  float* out = (float*)d_out;

  const size_t M = M_ROWS;
  float* ws = (float*)d_ws;
  float* T   = ws;             // M*256
  float* G1  = ws + M * 256;   // M*64
  float* X1  = ws + M * 320;   // M*64
  float* X2  = ws + M * 384;   // M*128
  float* H2  = ws + M * 512;   // M*128
  float* H3  = ws + M * 640;   // M*256
  unsigned long long* MASK = (unsigned long long*)(ws + M * 896);  // M*32 u64
  __hip_bfloat16* X1b = (__hip_bfloat16*)(ws + M * 960);   // M*64
  __hip_bfloat16* X2b = (__hip_bfloat16*)(ws + M * 992);   // M*128
  __hip_bfloat16* TB  = (__hip_bfloat16*)(ws + M * 1056);  // M*512
  __hip_bfloat16* G   = (__hip_bfloat16*)(ws + M * 1312);  // M*1024
  __hip_bfloat16* H3b = (__hip_bfloat16*)(ws + M * 1824);  // M*256
  __hip_bfloat16* WB  = (__hip_bfloat16*)(ws + M * 1952);
  if (ws_size < (size_t)M * 1984 * sizeof(float)) return;
  __hip_bfloat16* w_sa3_0 = WB;               // 256x128
  __hip_bfloat16* w_sa3_1 = w_sa3_0 + 32768;  // 256x256
  __hip_bfloat16* w_fp1_0 = w_sa3_1 + 65536;  // 512x128
  __hip_bfloat16* w_fp1_1 = w_fp1_0 + 65536;  // 512x512
  __hip_bfloat16* w_fp2_0 = w_fp1_1 + 262144; // 256x64
  __hip_bfloat16* w_fp2_1 = w_fp2_0 + 16384;  // 256x256
  __hip_bfloat16* w_fc1   = w_fp2_1 + 65536;  // 256x1024
  __hip_bfloat16* w_fc2   = w_fc1 + 262144;   // 128x256

  dim3 blk(256);
  TJobs jb;
  const float* srcs[8] = {sa3_w0, sa3_w1, fp1_w0, fp1_w1, fp2_w0, fp2_w1, fc1_w, fc2_w};
  __hip_bfloat16* dsts[8] = {w_sa3_0, w_sa3_1, w_fp1_0, w_fp1_1, w_fp2_0, w_fp2_1, w_fc1, w_fc2};
  int Ks[8] = {128, 256, 128, 512, 64, 256, 1024, 256};
  int Ns[8] = {256, 256, 512, 512, 256, 256, 256, 128};
  int off = 0;
  for (int i = 0; i < 8; i++) {
    jb.W[i] = srcs[i]; jb.Wt[i] = dsts[i];
    jb.K[i] = Ks[i]; jb.N[i] = Ns[i];
    jb.bx[i] = Ns[i] >> 5;
    jb.off[i] = off;
    off += (Ns[i] >> 5) * (Ks[i] >> 5);
  }
  transpose_cast_all<<<off, blk, 0, stream>>>(jb);

  // SA1 (fp32 exact).
  gemm_bias_relu<<<dim3(1, 256), blk, 0, stream>>>(x, 2, sa1_w0, sa1_b0, T, 64, 64, 2);
  gemm_bias_relu<<<dim3(1, 256), blk, 0, stream>>>(T, 64, sa1_w1, sa1_b1, G1, 64, 64, 64);
  knn_mean_kernel<<<16384, 256, 0, stream>>>(x, G1, X1, X1b);
  // SA2 (fp32 exact).
  gemm_bias_relu<<<dim3(2, 256), blk, 0, stream>>>(X1, 64, sa2_w0, sa2_b0, T, 128, 128, 64);
  gemm_bias_relu<<<dim3(2, 256), blk, 0, stream>>>(T, 128, sa2_w1, sa2_b1, H2, 128, 128, 128);
  ball_mask2<64><<<dim3(16, 128), blk, 0, stream>>>(X1, MASK, 0.2f * 0.2f);
  ball_gather_kernel<<<16384, 128, 0, stream>>>(MASK, H2, 128, X2, X2b, 128, 32);
  // SA3 MLP (bf16 MFMA).
  gemm_mfma<true><<<dim3(2, 128), blk, 0, stream>>>(X2b, 128, w_sa3_0, 128, sa3_b0, TB, 256, 256, 128);
  gemm_mfma<false><<<dim3(2, 128), blk, 0, stream>>>(TB, 256, w_sa3_1, 256, sa3_b1, H3, 256, 256, 256);
  ball_mask2<128><<<dim3(16, 128), blk, 0, stream>>>(X2, MASK, 0.4f * 0.4f);
  ball_gather_kernel<<<16384, 256, 0, stream>>>(MASK, H3, 256, nullptr, G + 768, 1024, 64);
  // FP1 (bf16).
  gemm_mfma<true><<<dim3(4, 128), blk, 0, stream>>>(X2b, 128, w_fp1_0, 128, fp1_b0, TB, 512, 512, 128);
  gemm_mfma<true><<<dim3(4, 128), blk, 0, stream>>>(TB, 512, w_fp1_1, 512, fp1_b1, G + 256, 1024, 512, 512);
  // FP2 (bf16).
  gemm_mfma<true><<<dim3(2, 128), blk, 0, stream>>>(X1b, 64, w_fp2_0, 64, fp2_b0, TB, 256, 256, 64);
  gemm_mfma<true><<<dim3(2, 128), blk, 0, stream>>>(TB, 256, w_fp2_1, 256, fp2_b1, G, 1024, 256, 256);
  // Head (bf16).
  gemm_mfma<true><<<dim3(2, 128), blk, 0, stream>>>(G, 1024, w_fc1, 1024, fc1_b, H3b, 256, 256, 1024);
  gemm_mfma<false><<<dim3(1, 128), blk, 0, stream>>>(H3b, 256, w_fc2, 256, fc2_b, H2, 128, 128, 256);
  out_kernel<<<16384, 128, 0, stream>>>(H2, out_w, out_b, out);
}

// Round 6
// 554.610 us; speedup vs baseline: 7.1301x; 1.1337x over previous
//
#include <hip/hip_runtime.h>
#include <hip/hip_bf16.h>
#include <cstdint>

#define M_ROWS 16384

typedef __attribute__((ext_vector_type(8))) short short8;
typedef __attribute__((ext_vector_type(4))) float f32x4;
typedef __attribute__((ext_vector_type(2))) float f32x2;

__device__ __forceinline__ unsigned long long umin64(unsigned long long a,
                                                     unsigned long long b) {
  return a < b ? a : b;
}

// ---------------------------------------------------------------------------
// fp32 GEMM (SA1/SA2 — feeds masks, bit-identical path).
// ---------------------------------------------------------------------------
__global__ __launch_bounds__(256) void gemm_bias_relu(
    const float* __restrict__ X, int ldx,
    const float* __restrict__ W,
    const float* __restrict__ bias,
    float* __restrict__ Y, int ldy,
    int N, int K)
{
  __shared__ __align__(16) float As[16][68];
  __shared__ __align__(16) float Bs[16][68];
  int tid = threadIdx.x;
  int tx = tid & 15, ty = tid >> 4;
  int m0 = blockIdx.y << 6, n0 = blockIdx.x << 6;
  float acc[4][4] = {};
  for (int k0 = 0; k0 < K; k0 += 16) {
#pragma unroll
    for (int i = 0; i < 4; i++) {
      int idx = tid + (i << 8);
      int m = idx >> 4, k = idx & 15;
      As[k][m] = (k0 + k < K) ? X[(size_t)(m0 + m) * ldx + k0 + k] : 0.f;
    }
#pragma unroll
    for (int i = 0; i < 4; i++) {
      int idx = tid + (i << 8);
      int n = idx & 63, k = idx >> 6;
      Bs[k][n] = (k0 + k < K) ? W[(size_t)(k0 + k) * N + n0 + n] : 0.f;
    }
    __syncthreads();
#pragma unroll
    for (int k = 0; k < 16; k++) {
      float4 a4 = *(const float4*)&As[k][ty << 2];
      float4 b4 = *(const float4*)&Bs[k][tx << 2];
      float av[4] = {a4.x, a4.y, a4.z, a4.w};
      float bv[4] = {b4.x, b4.y, b4.z, b4.w};
#pragma unroll
      for (int i = 0; i < 4; i++)
#pragma unroll
        for (int j = 0; j < 4; j++)
          acc[i][j] += av[i] * bv[j];
    }
    __syncthreads();
  }
  float4 bb = *(const float4*)&bias[n0 + (tx << 2)];
  float bv[4] = {bb.x, bb.y, bb.z, bb.w};
#pragma unroll
  for (int i = 0; i < 4; i++) {
    int m = m0 + (ty << 2) + i;
    float4 o;
    o.x = fmaxf(acc[i][0] + bv[0], 0.f);
    o.y = fmaxf(acc[i][1] + bv[1], 0.f);
    o.z = fmaxf(acc[i][2] + bv[2], 0.f);
    o.w = fmaxf(acc[i][3] + bv[3], 0.f);
    *(float4*)&Y[(size_t)m * ldy + n0 + (tx << 2)] = o;
  }
}

// ---------------------------------------------------------------------------
// Fused weight prep: 8 transposes (W KxN fp32 -> Wt NxK bf16) in one dispatch.
// ---------------------------------------------------------------------------
struct TJobs {
  const float* W[8];
  __hip_bfloat16* Wt[8];
  int K[8], N[8], bx[8], off[8];
};

__global__ __launch_bounds__(256) void transpose_cast_all(TJobs jb)
{
  __shared__ float tile[32][33];
  int bid = blockIdx.x;
  int j = 0;
#pragma unroll
  for (int t = 1; t < 8; t++)
    if (bid >= jb.off[t]) j = t;
  int rel = bid - jb.off[j];
  int K = jb.K[j], N = jb.N[j];
  const float* W = jb.W[j];
  __hip_bfloat16* Wt = jb.Wt[j];
  int n0 = (rel % jb.bx[j]) << 5, k0 = (rel / jb.bx[j]) << 5;
  int c = threadIdx.x & 31, i0 = threadIdx.x >> 5;
#pragma unroll
  for (int p = 0; p < 4; p++) {
    int i = i0 + p * 8;
    tile[i][c] = W[(size_t)(k0 + i) * N + n0 + c];
  }
  __syncthreads();
#pragma unroll
  for (int p = 0; p < 4; p++) {
    int r = i0 + p * 8;
    Wt[(size_t)(n0 + r) * K + k0 + c] = (__hip_bfloat16)tile[c][r];
  }
}

// ---------------------------------------------------------------------------
// bf16 MFMA GEMM (unchanged).
// ---------------------------------------------------------------------------
template <bool OUT_BF16>
__global__ __launch_bounds__(256) void gemm_mfma(
    const __hip_bfloat16* __restrict__ A, int lda,
    const __hip_bfloat16* __restrict__ Wt, int ldw,
    const float* __restrict__ bias,
    void* __restrict__ Y, int ldy, int N, int K)
{
  __shared__ __align__(16) short As[128][40];
  __shared__ __align__(16) short Bs[128][40];
  int tid = threadIdx.x;
  int wave = tid >> 6, lane = tid & 63;
  int quad = lane >> 4, l16 = lane & 15;
  int m0 = blockIdx.y << 7, n0 = blockIdx.x << 7;
  int wm = (wave >> 1) << 6, wn = (wave & 1) << 6;
  f32x4 acc[4][4] = {};
  const short* Ag = (const short*)A;
  const short* Bg = (const short*)Wt;
  int srow = tid >> 2, sq = tid & 3;
  for (int k0 = 0; k0 < K; k0 += 32) {
#pragma unroll
    for (int h = 0; h < 2; h++) {
      int r = srow + (h << 6);
      uint4 va = *(const uint4*)&Ag[(size_t)(m0 + r) * lda + k0 + sq * 8];
      *(uint4*)&As[r][sq * 8] = va;
      uint4 vb = *(const uint4*)&Bg[(size_t)(n0 + r) * ldw + k0 + sq * 8];
      *(uint4*)&Bs[r][sq * 8] = vb;
    }
    __syncthreads();
    short8 a[4], b[4];
#pragma unroll
    for (int mi = 0; mi < 4; mi++)
      a[mi] = *(const short8*)&As[wm + mi * 16 + l16][quad * 8];
#pragma unroll
    for (int ni = 0; ni < 4; ni++)
      b[ni] = *(const short8*)&Bs[wn + ni * 16 + l16][quad * 8];
#pragma unroll
    for (int mi = 0; mi < 4; mi++)
#pragma unroll
      for (int ni = 0; ni < 4; ni++)
        acc[mi][ni] = __builtin_amdgcn_mfma_f32_16x16x32_bf16(
            a[mi], b[ni], acc[mi][ni], 0, 0, 0);
    __syncthreads();
  }
  float bn[4];
#pragma unroll
  for (int ni = 0; ni < 4; ni++) bn[ni] = bias[n0 + wn + ni * 16 + l16];
#pragma unroll
  for (int mi = 0; mi < 4; mi++)
#pragma unroll
    for (int ni = 0; ni < 4; ni++) {
      int n = n0 + wn + ni * 16 + l16;
#pragma unroll
      for (int r = 0; r < 4; r++) {
        int m = m0 + wm + mi * 16 + quad * 4 + r;
        float v = fmaxf(acc[mi][ni][r] + bn[ni], 0.f);
        if (OUT_BF16)
          ((__hip_bfloat16*)Y)[(size_t)m * ldy + n] = (__hip_bfloat16)v;
        else
          ((float*)Y)[(size_t)m * ldy + n] = v;
      }
    }
}

// ---------------------------------------------------------------------------
// SA1 KNN v3 (round-5 version — threshold selection, passing).
// ---------------------------------------------------------------------------
__global__ __launch_bounds__(256) void knn_mean_kernel(
    const float* __restrict__ X,
    const float* __restrict__ G1,
    float* __restrict__ X1,
    __hip_bfloat16* __restrict__ X1b)
{
  int q = blockIdx.x;
  int base = q & ~2047;
  int tid = threadIdx.x;
  __shared__ unsigned long long lmins[256];
  __shared__ unsigned long long surv[2048];
  __shared__ unsigned long long thr;
  __shared__ int scnt;
  __shared__ int selidx[32];
  if (tid == 0) scnt = 0;
  float qx = X[(size_t)q * 2], qy = X[(size_t)q * 2 + 1];
  unsigned long long key[8];
#pragma unroll
  for (int u = 0; u < 8; u++) {
    int j = (u << 8) + tid;
    float dx = X[(size_t)(base + j) * 2] - qx;
    float dy = X[(size_t)(base + j) * 2 + 1] - qy;
    float d2 = dx * dx + dy * dy;
    key[u] = ((unsigned long long)__float_as_uint(d2) << 32) | (unsigned)j;
  }
  unsigned long long lm = key[0];
#pragma unroll
  for (int u = 1; u < 8; u++) lm = umin64(lm, key[u]);
  lmins[tid] = lm;
  __syncthreads();
  int rank = 0;
  for (int i = 0; i < 256; i++) rank += (lmins[i] < lm);
  if (rank == 31) thr = lm;
  __syncthreads();
  unsigned long long T = thr;
#pragma unroll
  for (int u = 0; u < 8; u++) {
    if (key[u] <= T) {
      int p = atomicAdd(&scnt, 1);
      surv[p] = key[u];
    }
  }
  __syncthreads();
  int s = scnt;
  for (int i = tid; i < s; i += 256) {
    unsigned long long c = surv[i];
    int r = 0;
    for (int j2 = 0; j2 < s; j2++) r += (surv[j2] < c);
    if (r < 32) selidx[r] = (int)(c & 0xffffffffULL);
  }
  __syncthreads();
  if (tid < 64) {
    float acc = 0.f;
#pragma unroll 4
    for (int sI = 0; sI < 32; sI++)
      acc += G1[(size_t)(base + selidx[sI]) * 64 + tid];
    float v = acc * (1.0f / 32.0f);
    X1[(size_t)q * 64 + tid] = v;
    X1b[(size_t)q * 64 + tid] = (__hip_bfloat16)v;
  }
}

// ---------------------------------------------------------------------------
// Ball-query pass 1 v4 — SYMMETRIC. d(q,c)=d(c,q) and fp32 (a-b)^2 ==
// (b-a)^2 exactly, so each off-diagonal 128x128 tile-pair is computed once
// and written to both mask[q][ct-words] (direct shfl-OR path) and
// mask[c][qt-words] (transposed, assembled via LDS atomicOr of 8-bit
// fields). Diagonal tiles: direct only (content identical). Per batch,
// 136 tile-pairs instead of 256. Packed-fp32 inner loop unchanged; NO
// min-occupancy launch bound (256,3 spilled the acc tile — 10x regression).
// ---------------------------------------------------------------------------
template <int C>
__global__ __launch_bounds__(256) void ball_mask_sym(
    const float* __restrict__ F,
    unsigned long long* __restrict__ mask,
    float r2)
{
  __shared__ __align__(16) float As[16][132];
  __shared__ __align__(16) float Bs[16][132];
  __shared__ unsigned int tw[128][4];  // transposed bits: [c-local][q-word32]
  int tid = threadIdx.x;
  int tx = tid & 15, ty = tid >> 4;
  // decode triangular pair (qt, ct), ct >= qt, 16 tiles/batch
  int p = blockIdx.x;
  int qt = 0;
  while (p >= 16 - qt) { p -= 16 - qt; qt++; }
  int ct = qt + p;
  int b0 = blockIdx.y << 11;
  int q0 = b0 + (qt << 7), c0 = b0 + (ct << 7);
  // zero transposed tile
  tw[tid >> 2][tid & 3] = 0;
  tw[(tid + 256) >> 2][tid & 3] = 0;
  f32x2 acc2[8][4] = {};
  for (int k0 = 0; k0 < C; k0 += 16) {
#pragma unroll
    for (int c = 0; c < 2; c++) {
      int idx = tid + (c << 8);
      int row = idx >> 2, qr = idx & 3;
      float4 va = *(const float4*)&F[(size_t)(q0 + row) * C + k0 + qr * 4];
      As[qr * 4 + 0][row] = va.x;
      As[qr * 4 + 1][row] = va.y;
      As[qr * 4 + 2][row] = va.z;
      As[qr * 4 + 3][row] = va.w;
      float4 vb = *(const float4*)&F[(size_t)(c0 + row) * C + k0 + qr * 4];
      Bs[qr * 4 + 0][row] = vb.x;
      Bs[qr * 4 + 1][row] = vb.y;
      Bs[qr * 4 + 2][row] = vb.z;
      Bs[qr * 4 + 3][row] = vb.w;
    }
    __syncthreads();
#pragma unroll
    for (int k = 0; k < 16; k++) {
      float av[8];
      f32x2 bv2[4];
      *(float4*)&av[0] = *(const float4*)&As[k][ty * 8];
      *(float4*)&av[4] = *(const float4*)&As[k][ty * 8 + 4];
      *(float4*)&bv2[0] = *(const float4*)&Bs[k][tx * 4];
      *(float4*)&bv2[2] = *(const float4*)&Bs[k][64 + tx * 4];
#pragma unroll
      for (int i = 0; i < 8; i++) {
        f32x2 a2 = {av[i], av[i]};
#pragma unroll
        for (int j2 = 0; j2 < 4; j2++) {
          f32x2 d = a2 - bv2[j2];
          acc2[i][j2] += d * d;
        }
      }
    }
    __syncthreads();
  }
  int w0 = ct << 1;
  unsigned int bytes[8] = {0, 0, 0, 0, 0, 0, 0, 0};
#pragma unroll
  for (int i = 0; i < 8; i++) {
    unsigned long long wlo = 0, whi = 0;
#pragma unroll
    for (int j = 0; j < 4; j++) {
      float dlo = acc2[i][j >> 1][j & 1];
      float dhi = acc2[i][2 + (j >> 1)][j & 1];
      if (dlo <= r2) { wlo |= 1ULL << (tx * 4 + j); bytes[j] |= 1u << i; }
      if (dhi <= r2) { whi |= 1ULL << (tx * 4 + j); bytes[4 + j] |= 1u << i; }
    }
#pragma unroll
    for (int s = 1; s <= 8; s <<= 1) {
      wlo |= __shfl_xor(wlo, s);
      whi |= __shfl_xor(whi, s);
    }
    if (tx == 0) {
      int q = q0 + ty * 8 + i;
      mask[(size_t)q * 32 + w0] = wlo;
      mask[(size_t)q * 32 + w0 + 1] = whi;
    }
  }
  if (qt != ct) {
    int sh = (ty & 3) * 8, wq = ty >> 2;
#pragma unroll
    for (int j2 = 0; j2 < 8; j2++) {
      int cl = ((j2 >> 2) << 6) + tx * 4 + (j2 & 3);
      atomicOr(&tw[cl][wq], bytes[j2] << sh);
    }
    __syncthreads();
    int row = tid >> 1, word = tid & 1;
    unsigned long long v = (unsigned long long)tw[row][word * 2] |
                           ((unsigned long long)tw[row][word * 2 + 1] << 32);
    mask[(size_t)(c0 + row) * 32 + (qt << 1) + word] = v;
  }
}

// ---------------------------------------------------------------------------
// Ball-query pass 2 (round-3/4 version — wave decode + unrollable sum).
// ---------------------------------------------------------------------------
__global__ void ball_gather_kernel(
    const unsigned long long* __restrict__ mask,
    const float* __restrict__ H, int CH,
    float* __restrict__ Yf, __hip_bfloat16* __restrict__ Yb,
    int ldy, int S)
{
  int q = blockIdx.x;
  int base = q & ~2047;
  int tid = threadIdx.x;
  __shared__ int idxl[64];
  __shared__ float wtab[64];
  __shared__ int scount;
  if (tid < 32) {
    unsigned long long w = mask[(size_t)q * 32 + tid];
    int cnt = __popcll(w);
    int inc = cnt;
#pragma unroll
    for (int off = 1; off < 32; off <<= 1) {
      int o = __shfl_up(inc, off);
      if (tid >= off) inc += o;
    }
    if (tid == 31) scount = inc;
    int p = inc - cnt;
    while (w && p < 64) {
      int j = (tid << 6) + __builtin_ctzll(w);
      w &= w - 1;
      idxl[p++] = j;
    }
  }
  __syncthreads();
  int c = scount;
  if (tid < 64) {
    int p = tid;
    int cnt = (p < c && p < S) ? ((S - 1 - p) / c + 1) : 0;
    wtab[p] = (float)cnt / (float)S;
  }
  __syncthreads();
  float acc = 0.f;
  int lim = c < S ? c : S;
#pragma unroll 4
  for (int s = 0; s < lim; s++)
    acc += wtab[s] * H[(size_t)(base + idxl[s]) * CH + tid];
  if (Yf) Yf[(size_t)q * ldy + tid] = acc;
  if (Yb) Yb[(size_t)q * ldy + tid] = (__hip_bfloat16)acc;
}

// ---------------------------------------------------------------------------
// Final head.
// ---------------------------------------------------------------------------
__global__ __launch_bounds__(128) void out_kernel(
    const float* __restrict__ F2,
    const float* __restrict__ w,
    const float* __restrict__ bias,
    float* __restrict__ out)
{
  int q = blockIdx.x, tid = threadIdx.x;
  float v = F2[(size_t)q * 128 + tid] * w[tid];
  for (int off = 32; off > 0; off >>= 1) v += __shfl_down(v, off);
  __shared__ float part[2];
  if ((tid & 63) == 0) part[tid >> 6] = v;
  __syncthreads();
  if (tid == 0) {
    float s = part[0] + part[1] + bias[0];
    out[q] = 1.f / (1.f + expf(-s));
  }
}

// ---------------------------------------------------------------------------
extern "C" void kernel_launch(void* const* d_in, const int* in_sizes, int n_in,
                              void* d_out, int out_size, void* d_ws,
                              size_t ws_size, hipStream_t stream)
{
  const float* x      = (const float*)d_in[0];
  const float* sa1_w0 = (const float*)d_in[1];
  const float* sa1_b0 = (const float*)d_in[2];
  const float* sa1_w1 = (const float*)d_in[3];
  const float* sa1_b1 = (const float*)d_in[4];
  const float* sa2_w0 = (const float*)d_in[5];
  const float* sa2_b0 = (const float*)d_in[6];
  const float* sa2_w1 = (const float*)d_in[7];
  const float* sa2_b1 = (const float*)d_in[8];
  const float* sa3_w0 = (const float*)d_in[9];
  const float* sa3_b0 = (const float*)d_in[10];
  const float* sa3_w1 = (const float*)d_in[11];
  const float* sa3_b1 = (const float*)d_in[12];
  const float* fp1_w0 = (const float*)d_in[13];
  const float* fp1_b0 = (const float*)d_in[14];
  const float* fp1_w1 = (const float*)d_in[15];
  const float* fp1_b1 = (const float*)d_in[16];
  const float* fp2_w0 = (const float*)d_in[17];
  const float* fp2_b0 = (const float*)d_in[18];
  const float* fp2_w1 = (const float*)d_in[19];
  const float* fp2_b1 = (const float*)d_in[20];
  const float* fc1_w  = (const float*)d_in[21];
  const float* fc1_b  = (const float*)d_in[22];
  const float* fc2_w  = (const float*)d_in[23];
  const float* fc2_b  = (const float*)d_in[24];
  const float* out_w  = (const float*)d_in[25];
  const float* out_b  = (const float*)d_in[26];
  float* out = (float*)d_out;

  const size_t M = M_ROWS;
  float* ws = (float*)d_ws;
  float* T   = ws;             // M*256
  float* G1  = ws + M * 256;   // M*64
  float* X1  = ws + M * 320;   // M*64
  float* X2  = ws + M * 384;   // M*128
  float* H2  = ws + M * 512;   // M*128
  float* H3  = ws + M * 640;   // M*256
  unsigned long long* MASK = (unsigned long long*)(ws + M * 896);  // M*32 u64
  __hip_bfloat16* X1b = (__hip_bfloat16*)(ws + M * 960);   // M*64
  __hip_bfloat16* X2b = (__hip_bfloat16*)(ws + M * 992);   // M*128
  __hip_bfloat16* TB  = (__hip_bfloat16*)(ws + M * 1056);  // M*512
  __hip_bfloat16* G   = (__hip_bfloat16*)(ws + M * 1312);  // M*1024
  __hip_bfloat16* H3b = (__hip_bfloat16*)(ws + M * 1824);  // M*256
  __hip_bfloat16* WB  = (__hip_bfloat16*)(ws + M * 1952);
  if (ws_size < (size_t)M * 1984 * sizeof(float)) return;
  __hip_bfloat16* w_sa3_0 = WB;               // 256x128
  __hip_bfloat16* w_sa3_1 = w_sa3_0 + 32768;  // 256x256
  __hip_bfloat16* w_fp1_0 = w_sa3_1 + 65536;  // 512x128
  __hip_bfloat16* w_fp1_1 = w_fp1_0 + 65536;  // 512x512
  __hip_bfloat16* w_fp2_0 = w_fp1_1 + 262144; // 256x64
  __hip_bfloat16* w_fp2_1 = w_fp2_0 + 16384;  // 256x256
  __hip_bfloat16* w_fc1   = w_fp2_1 + 65536;  // 256x1024
  __hip_bfloat16* w_fc2   = w_fc1 + 262144;   // 128x256

  dim3 blk(256);
  TJobs jb;
  const float* srcs[8] = {sa3_w0, sa3_w1, fp1_w0, fp1_w1, fp2_w0, fp2_w1, fc1_w, fc2_w};
  __hip_bfloat16* dsts[8] = {w_sa3_0, w_sa3_1, w_fp1_0, w_fp1_1, w_fp2_0, w_fp2_1, w_fc1, w_fc2};
  int Ks[8] = {128, 256, 128, 512, 64, 256, 1024, 256};
  int Ns[8] = {256, 256, 512, 512, 256, 256, 256, 128};
  int off = 0;
  for (int i = 0; i < 8; i++) {
    jb.W[i] = srcs[i]; jb.Wt[i] = dsts[i];
    jb.K[i] = Ks[i]; jb.N[i] = Ns[i];
    jb.bx[i] = Ns[i] >> 5;
    jb.off[i] = off;
    off += (Ns[i] >> 5) * (Ks[i] >> 5);
  }
  transpose_cast_all<<<off, blk, 0, stream>>>(jb);

  // SA1 (fp32 exact).
  gemm_bias_relu<<<dim3(1, 256), blk, 0, stream>>>(x, 2, sa1_w0, sa1_b0, T, 64, 64, 2);
  gemm_bias_relu<<<dim3(1, 256), blk, 0, stream>>>(T, 64, sa1_w1, sa1_b1, G1, 64, 64, 64);
  knn_mean_kernel<<<16384, 256, 0, stream>>>(x, G1, X1, X1b);
  // SA2 (fp32 exact).
  gemm_bias_relu<<<dim3(2, 256), blk, 0, stream>>>(X1, 64, sa2_w0, sa2_b0, T, 128, 128, 64);
  gemm_bias_relu<<<dim3(2, 256), blk, 0, stream>>>(T, 128, sa2_w1, sa2_b1, H2, 128, 128, 128);
  ball_mask_sym<64><<<dim3(136, 8), blk, 0, stream>>>(X1, MASK, 0.2f * 0.2f);
  ball_gather_kernel<<<16384, 128, 0, stream>>>(MASK, H2, 128, X2, X2b, 128, 32);
  // SA3 MLP (bf16 MFMA).
  gemm_mfma<true><<<dim3(2, 128), blk, 0, stream>>>(X2b, 128, w_sa3_0, 128, sa3_b0, TB, 256, 256, 128);
  gemm_mfma<false><<<dim3(2, 128), blk, 0, stream>>>(TB, 256, w_sa3_1, 256, sa3_b1, H3, 256, 256, 256);
  ball_mask_sym<128><<<dim3(136, 8), blk, 0, stream>>>(X2, MASK, 0.4f * 0.4f);
  ball_gather_kernel<<<16384, 256, 0, stream>>>(MASK, H3, 256, nullptr, G + 768, 1024, 64);
  // FP1 (bf16).
  gemm_mfma<true><<<dim3(4, 128), blk, 0, stream>>>(X2b, 128, w_fp1_0, 128, fp1_b0, TB, 512, 512, 128);
  gemm_mfma<true><<<dim3(4, 128), blk, 0, stream>>>(TB, 512, w_fp1_1, 512, fp1_b1, G + 256, 1024, 512, 512);
  // FP2 (bf16).
  gemm_mfma<true><<<dim3(2, 128), blk, 0, stream>>>(X1b, 64, w_fp2_0, 64, fp2_b0, TB, 256, 256, 64);
  gemm_mfma<true><<<dim3(2, 128), blk, 0, stream>>>(TB, 256, w_fp2_1, 256, fp2_b1, G, 1024, 256, 256);
  // Head (bf16).
  gemm_mfma<true><<<dim3(2, 128), blk, 0, stream>>>(G, 1024, w_fc1, 1024, fc1_b, H3b, 256, 256, 1024);
  gemm_mfma<false><<<dim3(1, 128), blk, 0, stream>>>(H3b, 256, w_fc2, 256, fc2_b, H2, 128, 128, 256);
  out_kernel<<<16384, 128, 0, stream>>>(H2, out_w, out_b, out);
}